// Round 6
// baseline (880.599 us; speedup 1.0000x reference)
//
#include <hip/hip_runtime.h>
#include <hip/hip_bf16.h>

// Problem constants
#define NROWS 16384      // B*C = 32*512
#define DDIM  256        // H*W
#define KEMB  8192
#define DECAYF 0.99f
#define ONE_MINUS_DECAY 0.01f
#define EPSF 1e-5f

// Output layout (all float32, concatenated in return order)
#define O_QST   0
#define O_LOSS  4194304
#define O_IDX   4194305
#define O_EMB   4210689
#define O_ECS   6307841
#define O_EES   6316033

typedef __attribute__((ext_vector_type(8))) short short8;
typedef __attribute__((ext_vector_type(4))) float f32x4;

// fp32 -> bf16 (RNE) as raw ushort, and back
static __device__ __forceinline__ unsigned short f2bf(float x) {
    unsigned int u = __float_as_uint(x);
    return (unsigned short)((u + 0x7fffu + ((u >> 16) & 1u)) >> 16);
}
static __device__ __forceinline__ float bf2f(unsigned short h) {
    return __uint_as_float(((unsigned int)h) << 16);
}

// Packed fragment layout: P[((g*32 + o)*16 + t)*8 + j] = M[g*16 + t][o*8 + j]
// (g = 16-row group, o = k-octet, t = row-in-group, j = elem)
// A wave's MFMA fragment load is then lane-contiguous 16B from global.

// ---------------- prep_z: convert + pack z; init key64 ----------------
// thread t: row r = t>>5, octet o = t&31  (reads wave-contiguous)
__global__ __launch_bounds__(256) void prep_z(const float* __restrict__ z,
                                              unsigned short* __restrict__ zh,
                                              unsigned short* __restrict__ zl,
                                              unsigned long long* __restrict__ key64) {
    const int t = blockIdx.x * 256 + threadIdx.x;
    const int r = t >> 5, o = t & 31;
    const float4 v0 = *(const float4*)&z[r * DDIM + o * 8];
    const float4 v1 = *(const float4*)&z[r * DDIM + o * 8 + 4];
    short8 h, l;
#pragma unroll
    for (int j = 0; j < 4; j++) {
        float x = ((const float*)&v0)[j];
        unsigned short hh = f2bf(x);
        h[j] = (short)hh; l[j] = (short)f2bf(x - bf2f(hh));
    }
#pragma unroll
    for (int j = 0; j < 4; j++) {
        float x = ((const float*)&v1)[j];
        unsigned short hh = f2bf(x);
        h[4 + j] = (short)hh; l[4 + j] = (short)f2bf(x - bf2f(hh));
    }
    const size_t p = ((size_t)((r >> 4) * 32 + o) * 16 + (r & 15)) * 8;
    *(short8*)&zh[p] = h;
    *(short8*)&zl[p] = l;
    if (o == 0) key64[r] = ~0ull;
}

// ---------------- prep_e: convert + pack emb; norms; ecs/ees decay ----------
__global__ __launch_bounds__(256) void prep_e(const float* __restrict__ emb,
                                              const float* __restrict__ ecs_in,
                                              const float* __restrict__ ees_in,
                                              float* __restrict__ enorm,
                                              unsigned short* __restrict__ eh,
                                              unsigned short* __restrict__ el,
                                              float* __restrict__ o_ecs,
                                              float* __restrict__ o_ees) {
    const int t = blockIdx.x * 256 + threadIdx.x;
    const int k = t >> 5, o = t & 31;
    const float4 v0 = *(const float4*)&emb[k * DDIM + o * 8];
    const float4 v1 = *(const float4*)&emb[k * DDIM + o * 8 + 4];
    short8 h, l;
    float s = 0.f;
#pragma unroll
    for (int j = 0; j < 4; j++) {
        float x = ((const float*)&v0)[j];
        s += x * x;
        unsigned short hh = f2bf(x);
        h[j] = (short)hh; l[j] = (short)f2bf(x - bf2f(hh));
    }
#pragma unroll
    for (int j = 0; j < 4; j++) {
        float x = ((const float*)&v1)[j];
        s += x * x;
        unsigned short hh = f2bf(x);
        h[4 + j] = (short)hh; l[4 + j] = (short)f2bf(x - bf2f(hh));
    }
    const size_t p = ((size_t)((k >> 4) * 32 + o) * 16 + (k & 15)) * 8;
    *(short8*)&eh[p] = h;
    *(short8*)&el[p] = l;
    // ees decay (coalesced, same addresses as emb reads)
    const float4 s0 = *(const float4*)&ees_in[k * DDIM + o * 8];
    const float4 s1 = *(const float4*)&ees_in[k * DDIM + o * 8 + 4];
    float4 d0, d1;
    d0.x = DECAYF * s0.x; d0.y = DECAYF * s0.y; d0.z = DECAYF * s0.z; d0.w = DECAYF * s0.w;
    d1.x = DECAYF * s1.x; d1.y = DECAYF * s1.y; d1.z = DECAYF * s1.z; d1.w = DECAYF * s1.w;
    *(float4*)&o_ees[k * DDIM + o * 8] = d0;
    *(float4*)&o_ees[k * DDIM + o * 8 + 4] = d1;
    // norm: reduce across the 32 lanes sharing k
    for (int m = 1; m < 32; m <<= 1) s += __shfl_xor(s, m);
    if (o == 0) {
        enorm[k] = s;
        o_ecs[k] = DECAYF * ecs_in[k];
    }
}

// ---------------- sum_ecs: scal[1]=0.99*sum(ecs), scal[0]=0 ----------------
__global__ __launch_bounds__(256) void sum_ecs(const float* __restrict__ ecs_in,
                                               float* __restrict__ scal) {
    float s = 0.f;
    for (int i = threadIdx.x; i < KEMB; i += 256) s += ecs_in[i];
    for (int o = 32; o; o >>= 1) s += __shfl_down(s, o);
    __shared__ float sh[4];
    if ((threadIdx.x & 63) == 0) sh[threadIdx.x >> 6] = s;
    __syncthreads();
    if (threadIdx.x == 0) {
        scal[1] = DECAYF * (sh[0] + sh[1] + sh[2] + sh[3]);
        scal[0] = 0.f;
    }
}

// ---------------- argmin_mfma: barrier-free bf16x3 GEMM + fused argmin ------
// Grid (128 row-blocks, 8 col-groups). Block 128 rows; loops 8 col-tiles of
// 128 cols. All fragments loaded directly from pre-packed global (no LDS
// staging, no K-loop barriers). Per-block best table in 1KB LDS.
__global__ __launch_bounds__(256) void argmin_mfma(const unsigned short* __restrict__ zh,
                                                   const unsigned short* __restrict__ zl,
                                                   const unsigned short* __restrict__ eh,
                                                   const unsigned short* __restrict__ el,
                                                   const float* __restrict__ enorm,
                                                   unsigned long long* __restrict__ key64) {
    __shared__ unsigned long long bestLds[128];

    const int tid = threadIdx.x;
    const int lane = tid & 63;
    const int wid = tid >> 6;
    const int wm = wid >> 1, wn = wid & 1;
    const int tx = lane & 15, quad = lane >> 4;

    const int row0 = blockIdx.x * 128;
    const int cg = blockIdx.y;               // col-group: cols [cg*1024, cg*1024+1024)

    if (tid < 128) bestLds[tid] = ~0ull;
    __syncthreads();

    // A base (shorts): g = row0/16 + wm*4 (+mi), addr = g*4096 + o*128 + tx*8,
    // o = ks*4 + quad
    const size_t aoff = (size_t)((row0 >> 4) + wm * 4) * 4096 + quad * 128 + tx * 8;
    const unsigned short* aHp = zh + aoff;
    const unsigned short* aLp = zl + aoff;

    for (int ct = 0; ct < 8; ++ct) {
        const int colbase = cg * 1024 + ct * 128;
        const size_t boff = (size_t)((colbase >> 4) + wn * 4) * 4096 + quad * 128 + tx * 8;
        const unsigned short* bHp = eh + boff;
        const unsigned short* bLp = el + boff;

        f32x4 acc[4][4];
#pragma unroll
        for (int i = 0; i < 4; i++)
#pragma unroll
            for (int j = 0; j < 4; j++) acc[i][j] = (f32x4){0.f, 0.f, 0.f, 0.f};

#pragma unroll
        for (int ks = 0; ks < 8; ++ks) {
            const size_t ko = (size_t)ks * 512;
            short8 aH[4], aL[4], bH[4], bL[4];
#pragma unroll
            for (int mi = 0; mi < 4; mi++) {
                aH[mi] = *(const short8*)(aHp + mi * 4096 + ko);
                aL[mi] = *(const short8*)(aLp + mi * 4096 + ko);
            }
#pragma unroll
            for (int nj = 0; nj < 4; nj++) {
                bH[nj] = *(const short8*)(bHp + nj * 4096 + ko);
                bL[nj] = *(const short8*)(bLp + nj * 4096 + ko);
            }
#pragma unroll
            for (int mi = 0; mi < 4; mi++)
#pragma unroll
                for (int nj = 0; nj < 4; nj++) {
                    acc[mi][nj] = __builtin_amdgcn_mfma_f32_16x16x32_bf16(aH[mi], bH[nj], acc[mi][nj], 0, 0, 0);
                    acc[mi][nj] = __builtin_amdgcn_mfma_f32_16x16x32_bf16(aL[mi], bH[nj], acc[mi][nj], 0, 0, 0);
                    acc[mi][nj] = __builtin_amdgcn_mfma_f32_16x16x32_bf16(aH[mi], bL[nj], acc[mi][nj], 0, 0, 0);
                }
        }

        // epilogue for this col-tile: dist = ||e||^2 - 2 x.e, k-ascending ties
        // C/D layout: col = tx (+nj*16), row = quad*4 + reg (+mi*16)
        float en[4];
        int colv[4];
#pragma unroll
        for (int nj = 0; nj < 4; nj++) {
            colv[nj] = colbase + wn * 64 + nj * 16 + tx;
            en[nj] = enorm[colv[nj]];
        }
#pragma unroll
        for (int mi = 0; mi < 4; mi++) {
#pragma unroll
            for (int r = 0; r < 4; r++) {
                unsigned long long best = ~0ull;
#pragma unroll
                for (int nj = 0; nj < 4; nj++) {
                    float d = en[nj] - 2.0f * acc[mi][nj][r];
                    unsigned int db = __float_as_uint(d);
                    db = (db & 0x80000000u) ? ~db : (db | 0x80000000u);
                    unsigned long long key = ((unsigned long long)db << 32) | (unsigned int)colv[nj];
                    if (key < best) best = key;
                }
#pragma unroll
                for (int m = 1; m < 16; m <<= 1) {
                    unsigned long long o = __shfl_xor(best, m);
                    if (o < best) best = o;
                }
                if (tx == 0)
                    atomicMin(&bestLds[wm * 64 + mi * 16 + quad * 4 + r], best);
            }
        }
    }

    __syncthreads();
    if (tid < 128) atomicMin(&key64[row0 + tid], bestLds[tid]);
}

// ---------------- quant_stats: 4 rows per wave, block-reduced loss ----------
__global__ __launch_bounds__(256) void quant_stats(const float* __restrict__ z,
                                                   const float* __restrict__ emb,
                                                   const unsigned long long* __restrict__ key64,
                                                   float* __restrict__ o_qst,
                                                   float* __restrict__ o_idx,
                                                   float* __restrict__ o_ecs,
                                                   float* __restrict__ o_ees,
                                                   float* __restrict__ scal) {
    const int w = threadIdx.x >> 6;
    const int lane = threadIdx.x & 63;
    const int nbase = blockIdx.x * 16 + w * 4;
    const int d0 = lane * 4;
    float ploc = 0.f;
#pragma unroll
    for (int r = 0; r < 4; r++) {
        const int n = nbase + r;
        const int k = (int)(key64[n] & 0xFFFFFFFFull);
        const float4 zv = *(const float4*)&z[n * DDIM + d0];
        const float4 ev = *(const float4*)&emb[k * DDIM + d0];
        const float dx = ev.x - zv.x, dy = ev.y - zv.y, dz2 = ev.z - zv.z, dw = ev.w - zv.w;
        float4 q;
        q.x = zv.x + dx; q.y = zv.y + dy; q.z = zv.z + dz2; q.w = zv.w + dw;
        *(float4*)&o_qst[n * DDIM + d0] = q;
        ploc += dx * dx + dy * dy + dz2 * dz2 + dw * dw;
        if (lane == 0) {
            o_idx[n] = (float)k;
            atomicAdd(&o_ecs[k], ONE_MINUS_DECAY);
        }
        atomicAdd(&o_ees[k * DDIM + d0 + 0], ONE_MINUS_DECAY * zv.x);
        atomicAdd(&o_ees[k * DDIM + d0 + 1], ONE_MINUS_DECAY * zv.y);
        atomicAdd(&o_ees[k * DDIM + d0 + 2], ONE_MINUS_DECAY * zv.z);
        atomicAdd(&o_ees[k * DDIM + d0 + 3], ONE_MINUS_DECAY * zv.w);
    }
    for (int o = 32; o; o >>= 1) ploc += __shfl_down(ploc, o);
    __shared__ float sh[4];
    if (lane == 0) sh[w] = ploc;
    __syncthreads();
    if (threadIdx.x == 0) atomicAdd(&scal[0], sh[0] + sh[1] + sh[2] + sh[3]);
}

// ---------------- finalize: new_embedding + loss scalar ----------------
// n_tot = 0.99*sum(ecs_in) + 0.01*NROWS   (scal[1] holds first term)
__global__ __launch_bounds__(256) void finalize_kernel(const float* __restrict__ o_ecs,
                                                       const float* __restrict__ o_ees,
                                                       const float* __restrict__ scal,
                                                       float* __restrict__ o_emb,
                                                       float* __restrict__ o_loss) {
    const int k = blockIdx.x;
    const int d = threadIdx.x;
    const float ntot = scal[1] + ONE_MINUS_DECAY * (float)NROWS;
    const float ecs = o_ecs[k];
    const float sm = (ecs + EPSF) / (ntot + (float)KEMB * EPSF) * ntot;
    o_emb[k * DDIM + d] = o_ees[k * DDIM + d] / sm;
    if (k == 0 && d == 0) o_loss[0] = 0.25f * scal[0] / (float)(NROWS * DDIM);
}

extern "C" void kernel_launch(void* const* d_in, const int* in_sizes, int n_in,
                              void* d_out, int out_size, void* d_ws, size_t ws_size,
                              hipStream_t stream) {
    const float* z   = (const float*)d_in[0];
    const float* emb = (const float*)d_in[1];
    const float* ecs = (const float*)d_in[2];
    const float* ees = (const float*)d_in[3];

    float* out = (float*)d_out;
    char*  ws  = (char*)d_ws;

    // small scratch at head of ws: norms (32KB), key64 (128KB), scal (8B)
    float* enorm = (float*)ws;                                    // 8192 f
    unsigned long long* key64 = (unsigned long long*)(ws + 32768);// 16384 u64
    float* scal = (float*)(ws + 32768 + 131072);

    // packed bf16 hi/lo scratch: prefer d_ws if large enough, else alias
    // output regions overwritten later (z-pack in O_QST, e-pack in O_EMB).
    const size_t big0 = 32768 + 131072 + 256;                     // 164 KB
    const size_t bigbytes = (size_t)(NROWS + KEMB) * DDIM * 2 * 2;// 24 MB
    unsigned short *zh, *zl, *ehp, *elp;
    if (ws_size >= big0 + bigbytes) {
        zh  = (unsigned short*)(ws + big0);
        zl  = zh + NROWS * DDIM;
        ehp = zl + NROWS * DDIM;
        elp = ehp + KEMB * DDIM;
    } else {
        zh  = (unsigned short*)(out + O_QST);
        zl  = zh + NROWS * DDIM;
        ehp = (unsigned short*)(out + O_EMB);
        elp = ehp + KEMB * DDIM;
    }

    prep_e<<<(KEMB * 32) / 256, 256, 0, stream>>>(emb, ecs, ees, enorm, ehp, elp,
                                                  out + O_ECS, out + O_EES);
    prep_z<<<(NROWS * 32) / 256, 256, 0, stream>>>(z, zh, zl, key64);
    sum_ecs<<<1, 256, 0, stream>>>(ecs, scal);
    argmin_mfma<<<dim3(NROWS / 128, 8), 256, 0, stream>>>(zh, zl, ehp, elp, enorm, key64);
    quant_stats<<<NROWS / 16, 256, 0, stream>>>(z, emb, key64, out + O_QST, out + O_IDX,
                                                out + O_ECS, out + O_EES, scal);
    finalize_kernel<<<KEMB, DDIM, 0, stream>>>(out + O_ECS, out + O_EES, scal,
                                               out + O_EMB, out + O_LOSS);
}

// Round 7
// 459.988 us; speedup vs baseline: 1.9144x; 1.9144x over previous
//
#include <hip/hip_runtime.h>
#include <hip/hip_bf16.h>

// Problem constants
#define NROWS 16384      // B*C = 32*512
#define DDIM  256        // H*W
#define KEMB  8192
#define DECAYF 0.99f
#define ONE_MINUS_DECAY 0.01f
#define EPSF 1e-5f

// Output layout (all float32, concatenated in return order)
#define O_QST   0
#define O_LOSS  4194304
#define O_IDX   4194305
#define O_EMB   4210689
#define O_ECS   6307841
#define O_EES   6316033

typedef __attribute__((ext_vector_type(8))) short short8;
typedef __attribute__((ext_vector_type(4))) float f32x4;

// fp32 -> bf16 (RNE) as raw ushort, and back
static __device__ __forceinline__ unsigned short f2bf(float x) {
    unsigned int u = __float_as_uint(x);
    return (unsigned short)((u + 0x7fffu + ((u >> 16) & 1u)) >> 16);
}
static __device__ __forceinline__ float bf2f(unsigned short h) {
    return __uint_as_float(((unsigned int)h) << 16);
}

// async global->LDS, 16B per lane; lds base wave-uniform, lane i lands at +16*i
static __device__ __forceinline__ void gload16(const unsigned short* g, unsigned short* l) {
    __builtin_amdgcn_global_load_lds(
        (const __attribute__((address_space(1))) unsigned int*)g,
        (__attribute__((address_space(3))) unsigned int*)l, 16, 0, 0);
}

// ---------------- prep_e: one wave per code k ----------------
// e-norm (fp32 exact) + e hi/lo bf16 split (row-major) + ecs/ees decay init
// + block-partial 0.99*sum(ecs) atomic into scal[1] (scal pre-zeroed by memset)
__global__ __launch_bounds__(256) void prep_e(const float* __restrict__ emb,
                                              const float* __restrict__ ecs_in,
                                              const float* __restrict__ ees_in,
                                              float* __restrict__ enorm,
                                              unsigned short* __restrict__ eh,
                                              unsigned short* __restrict__ el,
                                              float* __restrict__ o_ecs,
                                              float* __restrict__ o_ees,
                                              float* __restrict__ scal) {
    const int w = threadIdx.x >> 6;
    const int k = blockIdx.x * 4 + w;
    const int lane = threadIdx.x & 63;
    const int base = k * DDIM + lane * 4;
    const float4 v = *(const float4*)&emb[base];
    ushort4 h, l;
    {
        const float* vp = (const float*)&v;
        unsigned short hh;
        hh = f2bf(vp[0]); h.x = hh; l.x = f2bf(vp[0] - bf2f(hh));
        hh = f2bf(vp[1]); h.y = hh; l.y = f2bf(vp[1] - bf2f(hh));
        hh = f2bf(vp[2]); h.z = hh; l.z = f2bf(vp[2] - bf2f(hh));
        hh = f2bf(vp[3]); h.w = hh; l.w = f2bf(vp[3] - bf2f(hh));
    }
    *(ushort4*)&eh[base] = h;
    *(ushort4*)&el[base] = l;
    const float4 s = *(const float4*)&ees_in[base];
    float4 so;
    so.x = DECAYF * s.x; so.y = DECAYF * s.y; so.z = DECAYF * s.z; so.w = DECAYF * s.w;
    *(float4*)&o_ees[base] = so;
    float sum = v.x * v.x + v.y * v.y + v.z * v.z + v.w * v.w;
    for (int o = 32; o; o >>= 1) sum += __shfl_down(sum, o);
    __shared__ float sc[4];
    if (lane == 0) {
        enorm[k] = sum;
        const float c = DECAYF * ecs_in[k];
        o_ecs[k] = c;
        sc[w] = c;
    }
    __syncthreads();
    if (threadIdx.x == 0) atomicAdd(&scal[1], sc[0] + sc[1] + sc[2] + sc[3]);
}

// ---------------- prep_z: one wave per row ----------------
__global__ __launch_bounds__(256) void prep_z(const float* __restrict__ z,
                                              unsigned short* __restrict__ zh,
                                              unsigned short* __restrict__ zl,
                                              unsigned long long* __restrict__ key64) {
    const int n = blockIdx.x * 4 + (threadIdx.x >> 6);
    const int lane = threadIdx.x & 63;
    const int base = n * DDIM + lane * 4;
    const float4 v = *(const float4*)&z[base];
    ushort4 h, l;
    {
        const float* vp = (const float*)&v;
        unsigned short hh;
        hh = f2bf(vp[0]); h.x = hh; l.x = f2bf(vp[0] - bf2f(hh));
        hh = f2bf(vp[1]); h.y = hh; l.y = f2bf(vp[1] - bf2f(hh));
        hh = f2bf(vp[2]); h.z = hh; l.z = f2bf(vp[2] - bf2f(hh));
        hh = f2bf(vp[3]); h.w = hh; l.w = f2bf(vp[3] - bf2f(hh));
    }
    *(ushort4*)&zh[base] = h;
    *(ushort4*)&zl[base] = l;
    if (lane == 0) key64[n] = ~0ull;
}

// ---------------- argmin_mfma: bf16x3 MFMA GEMM + fused argmin (R3-exact) ---
// Block 128x128, 4 waves (2x2 of 64x64), BK=32, pre-split bf16 inputs,
// global_load_lds width=16 staging for both operands. Proven 315us config:
// 88 VGPR, 32KB LDS, ~5 blocks/CU -> barrier drain overlapped across blocks.
__global__ __launch_bounds__(256) void argmin_mfma(const unsigned short* __restrict__ zh,
                                                   const unsigned short* __restrict__ zl,
                                                   const unsigned short* __restrict__ eh,
                                                   const unsigned short* __restrict__ el,
                                                   const float* __restrict__ enorm,
                                                   unsigned long long* __restrict__ key64) {
    __shared__ unsigned short Ah[128][32];
    __shared__ unsigned short Al[128][32];
    __shared__ unsigned short Bh[128][32];
    __shared__ unsigned short Bl[128][32];

    const int tid = threadIdx.x;
    const int lane = tid & 63;
    const int wid = tid >> 6;
    const int wm = wid >> 1, wn = wid & 1;
    const int tx = lane & 15, quad = lane >> 4;

    const int row0 = blockIdx.x * 128;
    const int col0 = blockIdx.y * 128;

    // staging: wave w covers rows [w*32, w*32+32); lane l -> row l>>2, 16B chunk l&3
    const int w32 = wid * 32;
    const int r16 = lane >> 2;
    const int c8 = (lane & 3) * 8;

    f32x4 acc[4][4];
#pragma unroll
    for (int i = 0; i < 4; i++)
#pragma unroll
        for (int j = 0; j < 4; j++) acc[i][j] = (f32x4){0.f, 0.f, 0.f, 0.f};

    for (int dstep = 0; dstep < DDIM; dstep += 32) {
        __syncthreads();   // all waves done reading previous tiles
#pragma unroll
        for (int i = 0; i < 2; i++) {
            const int lr = w32 + i * 16;
            const size_t ga = (size_t)(row0 + lr + r16) * DDIM + dstep + c8;
            const size_t gb = (size_t)(col0 + lr + r16) * DDIM + dstep + c8;
            gload16(&zh[ga], &Ah[lr][0]);
            gload16(&zl[ga], &Al[lr][0]);
            gload16(&eh[gb], &Bh[lr][0]);
            gload16(&el[gb], &Bl[lr][0]);
        }
        __syncthreads();   // drains vmcnt: tiles resident

        short8 aH[4], aL[4], bH[4], bL[4];
        const int ar = wm * 64 + tx;
        const int br = wn * 64 + tx;
#pragma unroll
        for (int mi = 0; mi < 4; mi++) {
            aH[mi] = *(const short8*)&Ah[ar + mi * 16][quad * 8];
            aL[mi] = *(const short8*)&Al[ar + mi * 16][quad * 8];
        }
#pragma unroll
        for (int nj = 0; nj < 4; nj++) {
            bH[nj] = *(const short8*)&Bh[br + nj * 16][quad * 8];
            bL[nj] = *(const short8*)&Bl[br + nj * 16][quad * 8];
        }
#pragma unroll
        for (int mi = 0; mi < 4; mi++)
#pragma unroll
            for (int nj = 0; nj < 4; nj++) {
                acc[mi][nj] = __builtin_amdgcn_mfma_f32_16x16x32_bf16(aH[mi], bH[nj], acc[mi][nj], 0, 0, 0);
                acc[mi][nj] = __builtin_amdgcn_mfma_f32_16x16x32_bf16(aL[mi], bH[nj], acc[mi][nj], 0, 0, 0);
                acc[mi][nj] = __builtin_amdgcn_mfma_f32_16x16x32_bf16(aH[mi], bL[nj], acc[mi][nj], 0, 0, 0);
            }
    }

    // epilogue: dist = ||e||^2 - 2 x.e ; fused argmin, k-ascending tie-break.
    // C/D layout: col = lane&15 (+nj*16), row = quad*4 + reg (+mi*16)
    float en[4];
    int colv[4];
#pragma unroll
    for (int nj = 0; nj < 4; nj++) {
        colv[nj] = col0 + wn * 64 + nj * 16 + tx;
        en[nj] = enorm[colv[nj]];
    }
#pragma unroll
    for (int mi = 0; mi < 4; mi++) {
#pragma unroll
        for (int r = 0; r < 4; r++) {
            unsigned long long best = ~0ull;
#pragma unroll
            for (int nj = 0; nj < 4; nj++) {
                float d = en[nj] - 2.0f * acc[mi][nj][r];
                unsigned int db = __float_as_uint(d);
                db = (db & 0x80000000u) ? ~db : (db | 0x80000000u);
                unsigned long long key = ((unsigned long long)db << 32) | (unsigned int)colv[nj];
                if (key < best) best = key;
            }
#pragma unroll
            for (int m = 1; m < 16; m <<= 1) {
                unsigned long long o = __shfl_xor(best, m);
                if (o < best) best = o;
            }
            if (tx == 0)
                atomicMin(&key64[row0 + wm * 64 + mi * 16 + quad * 4 + r], best);
        }
    }
}

// ---------------- quant_stats: 4 rows per wave, block-reduced loss ----------
__global__ __launch_bounds__(256) void quant_stats(const float* __restrict__ z,
                                                   const float* __restrict__ emb,
                                                   const unsigned long long* __restrict__ key64,
                                                   float* __restrict__ o_qst,
                                                   float* __restrict__ o_idx,
                                                   float* __restrict__ o_ecs,
                                                   float* __restrict__ o_ees,
                                                   float* __restrict__ scal) {
    const int w = threadIdx.x >> 6;
    const int lane = threadIdx.x & 63;
    const int nbase = blockIdx.x * 16 + w * 4;
    const int d0 = lane * 4;
    float ploc = 0.f;
#pragma unroll
    for (int r = 0; r < 4; r++) {
        const int n = nbase + r;
        const int k = (int)(key64[n] & 0xFFFFFFFFull);
        const float4 zv = *(const float4*)&z[n * DDIM + d0];
        const float4 ev = *(const float4*)&emb[k * DDIM + d0];
        const float dx = ev.x - zv.x, dy = ev.y - zv.y, dz2 = ev.z - zv.z, dw = ev.w - zv.w;
        float4 q;
        q.x = zv.x + dx; q.y = zv.y + dy; q.z = zv.z + dz2; q.w = zv.w + dw;
        *(float4*)&o_qst[n * DDIM + d0] = q;
        ploc += dx * dx + dy * dy + dz2 * dz2 + dw * dw;
        if (lane == 0) {
            o_idx[n] = (float)k;
            atomicAdd(&o_ecs[k], ONE_MINUS_DECAY);
        }
        atomicAdd(&o_ees[k * DDIM + d0 + 0], ONE_MINUS_DECAY * zv.x);
        atomicAdd(&o_ees[k * DDIM + d0 + 1], ONE_MINUS_DECAY * zv.y);
        atomicAdd(&o_ees[k * DDIM + d0 + 2], ONE_MINUS_DECAY * zv.z);
        atomicAdd(&o_ees[k * DDIM + d0 + 3], ONE_MINUS_DECAY * zv.w);
    }
    for (int o = 32; o; o >>= 1) ploc += __shfl_down(ploc, o);
    __shared__ float sh[4];
    if (lane == 0) sh[w] = ploc;
    __syncthreads();
    if (threadIdx.x == 0) atomicAdd(&scal[0], sh[0] + sh[1] + sh[2] + sh[3]);
}

// ---------------- finalize: new_embedding + loss scalar ----------------
// n_tot = 0.99*sum(ecs_in) + 0.01*NROWS   (scal[1] holds first term)
__global__ __launch_bounds__(256) void finalize_kernel(const float* __restrict__ o_ecs,
                                                       const float* __restrict__ o_ees,
                                                       const float* __restrict__ scal,
                                                       float* __restrict__ o_emb,
                                                       float* __restrict__ o_loss) {
    const int k = blockIdx.x;
    const int d = threadIdx.x;
    const float ntot = scal[1] + ONE_MINUS_DECAY * (float)NROWS;
    const float ecs = o_ecs[k];
    const float sm = (ecs + EPSF) / (ntot + (float)KEMB * EPSF) * ntot;
    o_emb[k * DDIM + d] = o_ees[k * DDIM + d] / sm;
    if (k == 0 && d == 0) o_loss[0] = 0.25f * scal[0] / (float)(NROWS * DDIM);
}

extern "C" void kernel_launch(void* const* d_in, const int* in_sizes, int n_in,
                              void* d_out, int out_size, void* d_ws, size_t ws_size,
                              hipStream_t stream) {
    const float* z   = (const float*)d_in[0];
    const float* emb = (const float*)d_in[1];
    const float* ecs = (const float*)d_in[2];
    const float* ees = (const float*)d_in[3];

    float* out = (float*)d_out;
    char*  ws  = (char*)d_ws;

    // small scratch at head of ws: norms (32KB), key64 (128KB), scal (8B)
    float* enorm = (float*)ws;                                    // 8192 f
    unsigned long long* key64 = (unsigned long long*)(ws + 32768);// 16384 u64
    float* scal = (float*)(ws + 32768 + 131072);

    // bf16 hi/lo scratch: prefer d_ws if large enough, else alias output
    // regions overwritten later (zh/zl in O_QST, eh/el in O_EMB).
    const size_t big0 = 32768 + 131072 + 256;                     // 164 KB
    const size_t bigbytes = (size_t)(NROWS + KEMB) * DDIM * 2 * 2;// 24 MB
    unsigned short *zh, *zl, *ehp, *elp;
    if (ws_size >= big0 + bigbytes) {
        zh  = (unsigned short*)(ws + big0);
        zl  = zh + NROWS * DDIM;
        ehp = zl + NROWS * DDIM;
        elp = ehp + KEMB * DDIM;
    } else {
        zh  = (unsigned short*)(out + O_QST);
        zl  = zh + NROWS * DDIM;
        ehp = (unsigned short*)(out + O_EMB);
        elp = ehp + KEMB * DDIM;
    }

    hipMemsetAsync(scal, 0, 2 * sizeof(float), stream);
    prep_e<<<KEMB / 4, 256, 0, stream>>>(emb, ecs, ees, enorm, ehp, elp,
                                         out + O_ECS, out + O_EES, scal);
    prep_z<<<NROWS / 4, 256, 0, stream>>>(z, zh, zl, key64);
    argmin_mfma<<<dim3(NROWS / 128, KEMB / 128), 256, 0, stream>>>(zh, zl, ehp, elp, enorm, key64);
    quant_stats<<<NROWS / 16, 256, 0, stream>>>(z, emb, key64, out + O_QST, out + O_IDX,
                                                out + O_ECS, out + O_EES, scal);
    finalize_kernel<<<KEMB, DDIM, 0, stream>>>(out + O_ECS, out + O_EES, scal,
                                               out + O_EMB, out + O_LOSS);
}